// Round 10
// baseline (3913.266 us; speedup 1.0000x reference)
//
#include <hip/hip_runtime.h>
#include <hip/hip_fp16.h>
#include <cstdint>
#include <cstddef>

typedef _Float16 f16;
typedef __attribute__((ext_vector_type(8))) _Float16 f16x8;
typedef __attribute__((ext_vector_type(4))) _Float16 f16x4;
typedef __attribute__((ext_vector_type(2))) _Float16 f16x2;
typedef __attribute__((ext_vector_type(4))) float f32x4;

#define B_SZ 256
#define T_IN 1024
#define W_CH 512
#define U_N  512
#define P_K  16
#define TP   1009            // T_IN - P_K + 1
#define MROWS (B_SZ * TP)    // 258304

// ---------------------------------------------------------------------------
// Weight convert + transpose: fp32 [k][n] -> f16 [n][k].
// Kt: canonical k order (used by k_gemm).
// Rt: k-axis PERMUTED with pi(k) = (k & ~63) | ((k&15)<<2) | ((k>>4)&3) so the
// rnn state writes to LDS become contiguous stores. MFMA result is invariant
// to a shared k-permutation of A and B.
// ---------------------------------------------------------------------------
__global__ __launch_bounds__(256) void k_convert(
    const float* __restrict__ kern, const float* __restrict__ rec,
    f16* __restrict__ Kt, f16* __restrict__ Rt) {
  int idx = blockIdx.x * 256 + threadIdx.x;   // 0 .. 2*2^18
  int which = idx >> 18;
  int e = idx & 262143;
  int n = e >> 9;
  int k = e & 511;
  if (which == 0) {
    Kt[(size_t)n * 512 + k] = (f16)kern[(size_t)k * 512 + n];
  } else {
    int kp = (k & 448) | ((k & 15) << 2) | ((k >> 4) & 3);
    Rt[(size_t)n * 512 + kp] = (f16)rec[(size_t)k * 512 + n];
  }
}

// ---------------------------------------------------------------------------
// PSC conv: syn[b,t,w] = psc_b + sum_k psc_w[k] * x[b,t+k,w]   (f16 out)
// Thread owns (b, w-quad) and marches 64 t's with a 16-deep float4 ring.
// ---------------------------------------------------------------------------
__global__ __launch_bounds__(256) void k_conv(
    const float* __restrict__ x, const float* __restrict__ psc_w,
    const float* __restrict__ psc_b, f16* __restrict__ syn) {
  int g  = blockIdx.x * 256 + threadIdx.x;
  int wq = g & 127;              // w quad (4 floats)
  int tt = (g >> 7) & 15;        // t tile of 64
  int b  = g >> 11;
  int t0 = tt * 64;
  const float4* xr = (const float4*)x + (size_t)b * T_IN * 128 + wq;
  float wgt[16];
#pragma unroll
  for (int k = 0; k < 16; ++k) wgt[k] = psc_w[k];
  float b0 = psc_b[0];
  float4 win[16];
#pragma unroll
  for (int i = 0; i < 15; ++i) win[i] = xr[(size_t)(t0 + i) * 128];
  f16* sp = syn + ((size_t)b * TP + t0) * 512 + wq * 4;
  int steps = TP - t0; if (steps > 64) steps = 64;   // wave-uniform
  for (int j0 = 0; j0 < 64; j0 += 16) {
#pragma unroll
    for (int jj = 0; jj < 16; ++jj) {
      int j = j0 + jj;
      if (j < steps) {
        win[(j + 15) & 15] = xr[(size_t)(t0 + j + 15) * 128];
        float ax = b0, ay = b0, az = b0, aw = b0;
#pragma unroll
        for (int k = 0; k < 16; ++k) {
          float4 v = win[(j + k) & 15];
          float wk = wgt[k];
          ax += wk * v.x; ay += wk * v.y; az += wk * v.z; aw += wk * v.w;
        }
        f16x4 o; o.x = (f16)ax; o.y = (f16)ay; o.z = (f16)az; o.w = (f16)aw;
        *(f16x4*)(sp + (size_t)j * 512) = o;
      }
    }
  }
}

// ---------------------------------------------------------------------------
// Xp = syn @ K + bias  (fp32 result written into d_out, overwritten later by
// the recurrent kernel in place).  128x128 tile, BK=32, mfma 16x16x32 f16.
// ---------------------------------------------------------------------------
__global__ __launch_bounds__(256) void k_gemm(
    const f16* __restrict__ syn, const f16* __restrict__ Kt,
    const float* __restrict__ bias, float* __restrict__ out) {
  int bid = blockIdx.x;
  size_t m0 = (size_t)(bid >> 2) * 128;
  int n0 = (bid & 3) * 128;
  int tid = threadIdx.x;
  int wave = tid >> 6, lane = tid & 63;
  int q = lane >> 4, l15 = lane & 15;
  __shared__ f16 lA[128 * 32];
  __shared__ f16 lB[128 * 32];
  f32x4 acc[8][2] = {};
  int s0 = tid, s1 = tid + 256;
  int rA0 = s0 >> 2, cA0 = (s0 & 3) * 8;
  int rA1 = s1 >> 2, cA1 = (s1 & 3) * 8;
  for (int k0 = 0; k0 < 512; k0 += 32) {
    f16x8 a0 = *(const f16x8*)(syn + (m0 + rA0) * 512 + k0 + cA0);
    f16x8 a1 = *(const f16x8*)(syn + (m0 + rA1) * 512 + k0 + cA1);
    f16x8 b0 = *(const f16x8*)(Kt + (size_t)(n0 + rA0) * 512 + k0 + cA0);
    f16x8 b1 = *(const f16x8*)(Kt + (size_t)(n0 + rA1) * 512 + k0 + cA1);
    __syncthreads();                       // previous tile fully consumed
    *(f16x8*)(lA + s0 * 8) = a0;  *(f16x8*)(lA + s1 * 8) = a1;
    *(f16x8*)(lB + s0 * 8) = b0;  *(f16x8*)(lB + s1 * 8) = b1;
    __syncthreads();
    f16x8 bf[2];
#pragma unroll
    for (int j = 0; j < 2; ++j)
      bf[j] = *(const f16x8*)(lB + (wave * 32 + j * 16 + l15) * 32 + q * 8);
#pragma unroll
    for (int i = 0; i < 8; ++i) {
      f16x8 af = *(const f16x8*)(lA + (i * 16 + l15) * 32 + q * 8);
      acc[i][0] = __builtin_amdgcn_mfma_f32_16x16x32_f16(af, bf[0], acc[i][0], 0, 0, 0);
      acc[i][1] = __builtin_amdgcn_mfma_f32_16x16x32_f16(af, bf[1], acc[i][1], 0, 0, 0);
    }
  }
#pragma unroll
  for (int j = 0; j < 2; ++j) {
    int col = n0 + wave * 32 + j * 16 + l15;
    float bv = bias[col];
#pragma unroll
    for (int i = 0; i < 8; ++i) {
      size_t row = m0 + i * 16 + q * 4;
#pragma unroll
      for (int r = 0; r < 4; ++r)
        out[(row + r) * 512 + col] = acc[i][j][r] + bv;
    }
  }
}

// ---------------------------------------------------------------------------
// Sequential recurrence.  256 blocks x 1 batch, 1024 threads = 16 waves
// (4 waves/SIMD).  Round-10: the R9 step was LDS-pipe-bound (~94% busy;
// af broadcast reads alone ~2,048cy/CU-step, delivering 1KB of bus traffic
// per read for 64B of real state).  Fix: EXEC-MASKED af reads (R6-proven
// correct, conflict-free; R7's regression was 2 waves/SIMD having nothing
// to hide the serialization -- 4 waves/SIMD does).  afr[4] zero-init once;
// per batch, if(l15==0) 4x ds_read_b128 (4 active lanes, ~1-2cy each).
// Register budget (hard cap 128/wave for a 16-wave block):
//   rs[8][2]=64 (kk0-7) + afr[4]=16 + sw 16 + acc 8 + bf 8 + misc ~11.
// R split: kk0-7 registers, kk8-11 in the 128KB swizzled LDS tile,
// kk12-15 STREAMED from L2 (128KB/CU/step; all CUs fetch the same lines):
// kk12/13 prefetched cross-step (R constant, loads pend across the
// lgkm-only barrier), kk14/15 refilled mid-step and consumed >=150cy later.
// Consumption order: rs0-3, sw12/13 (+refill 14/15), rs4-7, sw14/15,
// tile8-11.  MFMA is accumulation-order-invariant.
// State: row 0 only, 2KB double-buffered SR.  One raw s_barrier per step
// (lgkmcnt drain only; global stores never drained in-loop).
// ---------------------------------------------------------------------------
__global__ __launch_bounds__(1024, 4) void k_rnn(
    const f16* __restrict__ Rt, float* __restrict__ io) {
  int b = blockIdx.x;             // one batch per block
  int tid = threadIdx.x, wave = tid >> 6, lane = tid & 63;
  int q = lane >> 4, l15 = lane & 15;
  __shared__ f16 R4[4 * 512 * 32];   // kk 8..11, [g][row][32k], swizzled (128KB)
  __shared__ f16 SR[2 * 512];        // state row 0 (pi layout), double-buffered

  // ---- stage R kk8..11 into LDS, swizzle: 16B slot c -> c ^ (row&3) ----
  {
    int row = tid & 511;
    int h = tid >> 9;                // 0/1: stage groups {0,1} / {2,3}
    const f16x8* src = (const f16x8*)(Rt + (size_t)row * 512 + 8 * 32);
#pragma unroll
    for (int gg = 0; gg < 2; ++gg) {
      int g = h * 2 + gg;
      char* dst = (char*)R4 + g * 32768 + row * 64;
#pragma unroll
      for (int c = 0; c < 4; ++c)
        *(f16x8*)(dst + ((c * 16) ^ ((row & 3) << 4))) = src[g * 4 + c];
    }
    if (tid < 512) { SR[tid] = (f16)0.f; SR[512 + tid] = (f16)0.f; }
  }

  int row0 = wave * 32 + l15;        // first owned unit (nt=0); nt=1 at +16
  // ---- kk0..7 register-resident: rs[8][2] = 64 regs ----
  const f16* rbase = Rt + (size_t)row0 * 512 + q * 8;
  f16x8 rs[8][2];
#pragma unroll
  for (int kk = 0; kk < 8; ++kk)
#pragma unroll
    for (int nt = 0; nt < 2; ++nt)
      rs[kk][nt] = *(const f16x8*)(rbase + (size_t)nt * 8192 + kk * 32);

  // per-lane R4 read base: row = row0 (+nt*16), slot q ^ (l15&3)
  const char* r4base = (const char*)R4 + row0 * 64
                       + ((q * 16) ^ ((l15 & 3) << 4));

  bool l0 = (l15 == 0);              // lanes carrying real A-row-0 fragments
  bool active = (q == 0);            // lanes carrying real C/D row 0

  f16x8 afr[4];                      // masked-read A buffer (16 regs)
#pragma unroll
  for (int i = 0; i < 4; ++i) afr[i] = (f16x8){};   // stays 0 for l15>0

  const f16* pc = SR + q * 8;        // af read base, current state buf
  const f16* pn = SR + 512 + q * 8;  // af read base, next state buf
  int wpos = (wave >> 1) * 64 + l15 * 4 + 2 * (wave & 1);
  f16* wc = SR + 512 + wpos;         // state write when reading SR0
  f16* wn = SR + wpos;               // state write when reading SR1

  unsigned ioff = (unsigned)b * (TP * 512u) + (unsigned)row0;
  float xp0 = io[ioff], xp1 = io[ioff + 16u];

  // ---- prologue stream: kk12 -> swA, kk13 -> swB ----
  f16x8 swA[2], swB[2];
  swA[0] = *(const f16x8*)(rbase + 12 * 32);
  swA[1] = *(const f16x8*)(rbase + 8192 + 12 * 32);
  swB[0] = *(const f16x8*)(rbase + 13 * 32);
  swB[1] = *(const f16x8*)(rbase + 8192 + 13 * 32);

  __syncthreads();

  for (int t = 0; t < TP; ++t) {
    f32x4 a0 = {}, a1 = {};
    // ---- batch 1: af {0,1,2,3}, MFMA vs rs ----
    if (l0) {
#pragma unroll
      for (int i = 0; i < 4; ++i) afr[i] = *(const f16x8*)(pc + i * 32);
    }
#pragma unroll
    for (int kk = 0; kk < 4; ++kk) {
      a0 = __builtin_amdgcn_mfma_f32_16x16x32_f16(afr[kk], rs[kk][0], a0, 0, 0, 0);
      a1 = __builtin_amdgcn_mfma_f32_16x16x32_f16(afr[kk], rs[kk][1], a1, 0, 0, 0);
    }
    // ---- batch 2: af {12,13,4,5}; consume swA/swB, refill kk14/15 ----
    if (l0) {
      afr[0] = *(const f16x8*)(pc + 12 * 32);
      afr[1] = *(const f16x8*)(pc + 13 * 32);
      afr[2] = *(const f16x8*)(pc + 4 * 32);
      afr[3] = *(const f16x8*)(pc + 5 * 32);
    }
    a0 = __builtin_amdgcn_mfma_f32_16x16x32_f16(afr[0], swA[0], a0, 0, 0, 0);
    a1 = __builtin_amdgcn_mfma_f32_16x16x32_f16(afr[0], swA[1], a1, 0, 0, 0);
    a0 = __builtin_amdgcn_mfma_f32_16x16x32_f16(afr[1], swB[0], a0, 0, 0, 0);
    a1 = __builtin_amdgcn_mfma_f32_16x16x32_f16(afr[1], swB[1], a1, 0, 0, 0);
    swA[0] = *(const f16x8*)(rbase + 14 * 32);              // refill kk14
    swA[1] = *(const f16x8*)(rbase + 8192 + 14 * 32);
    swB[0] = *(const f16x8*)(rbase + 15 * 32);              // refill kk15
    swB[1] = *(const f16x8*)(rbase + 8192 + 15 * 32);
    a0 = __builtin_amdgcn_mfma_f32_16x16x32_f16(afr[2], rs[4][0], a0, 0, 0, 0);
    a1 = __builtin_amdgcn_mfma_f32_16x16x32_f16(afr[2], rs[4][1], a1, 0, 0, 0);
    a0 = __builtin_amdgcn_mfma_f32_16x16x32_f16(afr[3], rs[5][0], a0, 0, 0, 0);
    a1 = __builtin_amdgcn_mfma_f32_16x16x32_f16(afr[3], rs[5][1], a1, 0, 0, 0);
    // ---- batch 3: af {6,7,14,15}; rs6/7 first (covers kk14/15 latency) ----
    if (l0) {
      afr[0] = *(const f16x8*)(pc + 6 * 32);
      afr[1] = *(const f16x8*)(pc + 7 * 32);
      afr[2] = *(const f16x8*)(pc + 14 * 32);
      afr[3] = *(const f16x8*)(pc + 15 * 32);
    }
    a0 = __builtin_amdgcn_mfma_f32_16x16x32_f16(afr[0], rs[6][0], a0, 0, 0, 0);
    a1 = __builtin_amdgcn_mfma_f32_16x16x32_f16(afr[0], rs[6][1], a1, 0, 0, 0);
    a0 = __builtin_amdgcn_mfma_f32_16x16x32_f16(afr[1], rs[7][0], a0, 0, 0, 0);
    a1 = __builtin_amdgcn_mfma_f32_16x16x32_f16(afr[1], rs[7][1], a1, 0, 0, 0);
    a0 = __builtin_amdgcn_mfma_f32_16x16x32_f16(afr[2], swA[0], a0, 0, 0, 0);
    a1 = __builtin_amdgcn_mfma_f32_16x16x32_f16(afr[2], swA[1], a1, 0, 0, 0);
    a0 = __builtin_amdgcn_mfma_f32_16x16x32_f16(afr[3], swB[0], a0, 0, 0, 0);
    a1 = __builtin_amdgcn_mfma_f32_16x16x32_f16(afr[3], swB[1], a1, 0, 0, 0);
    // ---- batch 4: af {8,9,10,11}, B from LDS tile (swizzled) ----
    if (l0) {
#pragma unroll
      for (int i = 0; i < 4; ++i) afr[i] = *(const f16x8*)(pc + (8 + i) * 32);
    }
#pragma unroll
    for (int g = 0; g < 4; ++g) {
      f16x8 bf0 = *(const f16x8*)(r4base + g * 32768);
      f16x8 bf1 = *(const f16x8*)(r4base + g * 32768 + 1024);
      a0 = __builtin_amdgcn_mfma_f32_16x16x32_f16(afr[g], bf0, a0, 0, 0, 0);
      a1 = __builtin_amdgcn_mfma_f32_16x16x32_f16(afr[g], bf1, a1, 0, 0, 0);
    }
    // ---- epilogue: row 0 only; n -> io, new state -> next buffer ----
    {
      float o0 = a0[0] + xp0;
      float o1 = a1[0] + xp1;
      float n0 = __builtin_amdgcn_rcpf(1.f + __builtin_amdgcn_exp2f(-4.3280850f * o0));
      float n1 = __builtin_amdgcn_rcpf(1.f + __builtin_amdgcn_exp2f(-4.3280850f * o1));
      float g0 = __builtin_amdgcn_rcpf(1.f + __builtin_amdgcn_exp2f((2.f * n0 - 1.f) * 1.4426950f));
      float g1 = __builtin_amdgcn_rcpf(1.f + __builtin_amdgcn_exp2f((2.f * n1 - 1.f) * 1.4426950f));
      if (active) {
        io[ioff]       = n0;                    // n overwrites Xp
        io[ioff + 16u] = n1;
        f16x2 sv; sv.x = (f16)(o0 * g0); sv.y = (f16)(o1 * g1);
        *(f16x2*)wc = sv;                       // pi-layout state write
      }
    }
    ioff += 512u;
    if (t < TP - 1) {
      xp0 = io[ioff]; xp1 = io[ioff + 16u];     // prefetch Xp[t+1]
      // cross-step prefetch of next step's kk12/13 (R constant; these VMEM
      // loads stay pending across the lgkm-only barrier)
      swA[0] = *(const f16x8*)(rbase + 12 * 32);
      swA[1] = *(const f16x8*)(rbase + 8192 + 12 * 32);
      swB[0] = *(const f16x8*)(rbase + 13 * 32);
      swB[1] = *(const f16x8*)(rbase + 8192 + 13 * 32);
    }
    // Single barrier per step: drain LDS (state write) only; global stores
    // are disjoint-address and never drained in-loop.
    asm volatile("s_waitcnt lgkmcnt(0)\n\ts_barrier" ::: "memory");
    const f16* tp = pc; pc = pn; pn = tp;
    f16* tw = wc; wc = wn; wn = tw;
  }
}

// ---------------------------------------------------------------------------
extern "C" void kernel_launch(void* const* d_in, const int* in_sizes, int n_in,
                              void* d_out, int out_size, void* d_ws, size_t ws_size,
                              hipStream_t stream) {
  (void)in_sizes; (void)n_in; (void)out_size; (void)ws_size;
  const float* x     = (const float*)d_in[0];
  const float* psc_w = (const float*)d_in[1];
  const float* psc_b = (const float*)d_in[2];
  const float* kern  = (const float*)d_in[3];
  const float* rec   = (const float*)d_in[4];
  const float* bias  = (const float*)d_in[5];
  float* out = (float*)d_out;
  char* ws = (char*)d_ws;
  // ws layout: syn f16 (258304*512*2 = 264,503,296 B) | Kt f16 512KB | Rt f16 512KB
  f16* syn = (f16*)ws;
  f16* Kt  = (f16*)(ws + 264503296ull);
  f16* Rt  = (f16*)(ws + 265027584ull);

  k_convert<<<2048, 256, 0, stream>>>(kern, rec, Kt, Rt);
  k_conv   <<<2048, 256, 0, stream>>>(x, psc_w, psc_b, syn);
  k_gemm   <<<2018 * 4, 256, 0, stream>>>(syn, Kt, bias, out);
  k_rnn    <<<256, 1024, 0, stream>>>(Rt, out);
}

// Round 11
// 2717.056 us; speedup vs baseline: 1.4403x; 1.4403x over previous
//
#include <hip/hip_runtime.h>
#include <hip/hip_fp16.h>
#include <cstdint>
#include <cstddef>

typedef _Float16 f16;
typedef __attribute__((ext_vector_type(8))) _Float16 f16x8;
typedef __attribute__((ext_vector_type(4))) _Float16 f16x4;
typedef __attribute__((ext_vector_type(2))) _Float16 f16x2;
typedef __attribute__((ext_vector_type(4))) float f32x4;

#define B_SZ 256
#define T_IN 1024
#define W_CH 512
#define U_N  512
#define P_K  16
#define TP   1009            // T_IN - P_K + 1
#define MROWS (B_SZ * TP)    // 258304

// ---------------------------------------------------------------------------
// Weight convert + transpose: fp32 [k][n] -> f16 [n][k].
// Kt: canonical k order (used by k_gemm).
// Rt: k-axis PERMUTED with pi(k) = (k & ~63) | ((k&15)<<2) | ((k>>4)&3) so the
// rnn state writes to LDS become contiguous stores. MFMA result is invariant
// to a shared k-permutation of A and B.
// ---------------------------------------------------------------------------
__global__ __launch_bounds__(256) void k_convert(
    const float* __restrict__ kern, const float* __restrict__ rec,
    f16* __restrict__ Kt, f16* __restrict__ Rt) {
  int idx = blockIdx.x * 256 + threadIdx.x;   // 0 .. 2*2^18
  int which = idx >> 18;
  int e = idx & 262143;
  int n = e >> 9;
  int k = e & 511;
  if (which == 0) {
    Kt[(size_t)n * 512 + k] = (f16)kern[(size_t)k * 512 + n];
  } else {
    int kp = (k & 448) | ((k & 15) << 2) | ((k >> 4) & 3);
    Rt[(size_t)n * 512 + kp] = (f16)rec[(size_t)k * 512 + n];
  }
}

// ---------------------------------------------------------------------------
// PSC conv: syn[b,t,w] = psc_b + sum_k psc_w[k] * x[b,t+k,w]   (f16 out)
// Thread owns (b, w-quad) and marches 64 t's with a 16-deep float4 ring.
// ---------------------------------------------------------------------------
__global__ __launch_bounds__(256) void k_conv(
    const float* __restrict__ x, const float* __restrict__ psc_w,
    const float* __restrict__ psc_b, f16* __restrict__ syn) {
  int g  = blockIdx.x * 256 + threadIdx.x;
  int wq = g & 127;              // w quad (4 floats)
  int tt = (g >> 7) & 15;        // t tile of 64
  int b  = g >> 11;
  int t0 = tt * 64;
  const float4* xr = (const float4*)x + (size_t)b * T_IN * 128 + wq;
  float wgt[16];
#pragma unroll
  for (int k = 0; k < 16; ++k) wgt[k] = psc_w[k];
  float b0 = psc_b[0];
  float4 win[16];
#pragma unroll
  for (int i = 0; i < 15; ++i) win[i] = xr[(size_t)(t0 + i) * 128];
  f16* sp = syn + ((size_t)b * TP + t0) * 512 + wq * 4;
  int steps = TP - t0; if (steps > 64) steps = 64;   // wave-uniform
  for (int j0 = 0; j0 < 64; j0 += 16) {
#pragma unroll
    for (int jj = 0; jj < 16; ++jj) {
      int j = j0 + jj;
      if (j < steps) {
        win[(j + 15) & 15] = xr[(size_t)(t0 + j + 15) * 128];
        float ax = b0, ay = b0, az = b0, aw = b0;
#pragma unroll
        for (int k = 0; k < 16; ++k) {
          float4 v = win[(j + k) & 15];
          float wk = wgt[k];
          ax += wk * v.x; ay += wk * v.y; az += wk * v.z; aw += wk * v.w;
        }
        f16x4 o; o.x = (f16)ax; o.y = (f16)ay; o.z = (f16)az; o.w = (f16)aw;
        *(f16x4*)(sp + (size_t)j * 512) = o;
      }
    }
  }
}

// ---------------------------------------------------------------------------
// Xp = syn @ K + bias  (fp32 result written into d_out, overwritten later by
// the recurrent kernel in place).  128x128 tile, BK=32, mfma 16x16x32 f16.
// ---------------------------------------------------------------------------
__global__ __launch_bounds__(256) void k_gemm(
    const f16* __restrict__ syn, const f16* __restrict__ Kt,
    const float* __restrict__ bias, float* __restrict__ out) {
  int bid = blockIdx.x;
  size_t m0 = (size_t)(bid >> 2) * 128;
  int n0 = (bid & 3) * 128;
  int tid = threadIdx.x;
  int wave = tid >> 6, lane = tid & 63;
  int q = lane >> 4, l15 = lane & 15;
  __shared__ f16 lA[128 * 32];
  __shared__ f16 lB[128 * 32];
  f32x4 acc[8][2] = {};
  int s0 = tid, s1 = tid + 256;
  int rA0 = s0 >> 2, cA0 = (s0 & 3) * 8;
  int rA1 = s1 >> 2, cA1 = (s1 & 3) * 8;
  for (int k0 = 0; k0 < 512; k0 += 32) {
    f16x8 a0 = *(const f16x8*)(syn + (m0 + rA0) * 512 + k0 + cA0);
    f16x8 a1 = *(const f16x8*)(syn + (m0 + rA1) * 512 + k0 + cA1);
    f16x8 b0 = *(const f16x8*)(Kt + (size_t)(n0 + rA0) * 512 + k0 + cA0);
    f16x8 b1 = *(const f16x8*)(Kt + (size_t)(n0 + rA1) * 512 + k0 + cA1);
    __syncthreads();                       // previous tile fully consumed
    *(f16x8*)(lA + s0 * 8) = a0;  *(f16x8*)(lA + s1 * 8) = a1;
    *(f16x8*)(lB + s0 * 8) = b0;  *(f16x8*)(lB + s1 * 8) = b1;
    __syncthreads();
    f16x8 bf[2];
#pragma unroll
    for (int j = 0; j < 2; ++j)
      bf[j] = *(const f16x8*)(lB + (wave * 32 + j * 16 + l15) * 32 + q * 8);
#pragma unroll
    for (int i = 0; i < 8; ++i) {
      f16x8 af = *(const f16x8*)(lA + (i * 16 + l15) * 32 + q * 8);
      acc[i][0] = __builtin_amdgcn_mfma_f32_16x16x32_f16(af, bf[0], acc[i][0], 0, 0, 0);
      acc[i][1] = __builtin_amdgcn_mfma_f32_16x16x32_f16(af, bf[1], acc[i][1], 0, 0, 0);
    }
  }
#pragma unroll
  for (int j = 0; j < 2; ++j) {
    int col = n0 + wave * 32 + j * 16 + l15;
    float bv = bias[col];
#pragma unroll
    for (int i = 0; i < 8; ++i) {
      size_t row = m0 + i * 16 + q * 4;
#pragma unroll
      for (int r = 0; r < 4; ++r)
        out[(row + r) * 512 + col] = acc[i][j][r] + bv;
    }
  }
}

// ---------------------------------------------------------------------------
// Sequential recurrence.  256 blocks x 1 batch, 1024 threads = 16 waves
// (4 waves/SIMD).  Round-11 = the R9 structure (best: 1,624us) + 3 fixes:
//  (1) TILE ROW PERMUTATION p(r) = swap bits 0<->2 of r (staging AND read
//      base).  The conflict counter tracks tile bf reads (R6=0 tiles->0;
//      R8=3 groups->0.99e8; 4 groups->1.325e8 = 4 extra cy per read): LDS
//      processes 8 consecutive lanes per phase (fixed q, l15 0..7), and the
//      old quad map 4*(l15&1)+(q^(l15&3)) collides l15 vs l15+4.  With p,
//      quad = 4*(l15 bit2)+(q^(l15&3)) is bijective per phase group ->
//      8-cy floor per read, conflicts ~0.
//  (2) s_setprio(1) around the MFMA block (T5): waves drift within a step;
//      MFMA-phase waves get issue priority over epilogue-phase waves.
//  (3) EPILOGUE SPLIT: state chain + SR write pre-barrier (the true
//      dependency); io n-stores + xp prefetch post-barrier, overlapping the
//      next step's MFMA phase instead of the barrier tail.
// R split: kk0..10 register-resident rs[11][2] (88 regs), kk11..14 in the
// 128KB permuted+swizzled LDS tile, kk15 streamed from L2 (32KB/step,
// step-top issue, consumed last).  af: zero-region broadcast (l15>0 lanes
// read a never-written LDS zero region; bank-quads disjoint from state).
// State: row 0 only, double-buffered in SRZ.  One raw s_barrier per step
// (lgkmcnt drain only; global stores never drained in-loop).
// Step model: MFMA pipe 2,483cy/SIMD (19.4cy per 16x16x32 per SIMD) is the
// floor; R9 step 3,864cy = MFMA 64% + VALU 35% phase-locked.
// ---------------------------------------------------------------------------
__global__ __launch_bounds__(1024, 4) void k_rnn(
    const f16* __restrict__ Rt, float* __restrict__ io) {
  int b = blockIdx.x;             // one batch per block
  int tid = threadIdx.x, wave = tid >> 6, lane = tid & 63;
  int q = lane >> 4, l15 = lane & 15;
  __shared__ f16 R4[4 * 512 * 32];           // kk 11..14, swizzled (128KB)
  // SRZ: [SR0 512][SR1 512][pad 32][Z 544] halves.  Zero region at offset
  // 1056 halfs = 132 sixteen-B units; 132%8=4 and (132-64)%8=4 -> disjoint
  // bank-quads from both state buffers.
  __shared__ __align__(64) f16 SRZ[1600];

  // ---- stage R kk11..14: row r -> physical row p(r) (bits 0<->2 swapped),
  //      16B slot c stored at byte (c*16) ^ ((r&3)<<4) ----
  {
    int row = tid & 511;
    int h = tid >> 9;                // 0/1: stage groups {0,1} / {2,3}
    int prow = (row & ~5) | ((row & 1) << 2) | ((row >> 2) & 1);
    const f16x8* src = (const f16x8*)(Rt + (size_t)row * 512 + 11 * 32);
#pragma unroll
    for (int gg = 0; gg < 2; ++gg) {
      int g = h * 2 + gg;
      char* dst = (char*)R4 + g * 32768 + prow * 64;
#pragma unroll
      for (int c = 0; c < 4; ++c)
        *(f16x8*)(dst + ((c * 16) ^ ((row & 3) << 4))) = src[g * 4 + c];
    }
    for (int i = tid; i < 1600; i += 1024) SRZ[i] = (f16)0.f;
  }

  int row0 = wave * 32 + l15;        // first owned unit (nt=0); nt=1 at +16
  // ---- kk0..10 register-resident: rs[11][2] = 88 regs ----
  const f16* rbase = Rt + (size_t)row0 * 512 + q * 8;
  f16x8 rs[11][2];
#pragma unroll
  for (int kk = 0; kk < 11; ++kk)
#pragma unroll
    for (int nt = 0; nt < 2; ++nt)
      rs[kk][nt] = *(const f16x8*)(rbase + (size_t)nt * 8192 + kk * 32);

  // per-lane R4 read base: physical row p(row0) = wave*32 + p(l15), slot
  // q ^ (l15&3).  nt=1 is +16 rows = +1024B (bit4 untouched by p).
  int pl = (l15 & ~5) | ((l15 & 1) << 2) | ((l15 >> 2) & 1);
  const char* r4base = (const char*)R4 + (size_t)(wave * 32 + pl) * 64
                       + ((q * 16) ^ ((l15 & 3) << 4));

  bool l0 = (l15 == 0);
  const f16* zb = SRZ + 1056 + q * 8;            // zero region (never written)
  const f16* pc = l0 ? (SRZ + q * 8)       : zb; // af base, current state buf
  const f16* pn = l0 ? (SRZ + 512 + q * 8) : zb; // af base, next state buf
  int wpos = (wave >> 1) * 64 + l15 * 4 + 2 * (wave & 1);
  f16* wc = SRZ + 512 + wpos;        // state write when reading SR0
  f16* wn = SRZ + wpos;              // state write when reading SR1

  bool active = (q == 0);            // only C/D row 0 is real
  unsigned ioff = (unsigned)b * (TP * 512u) + (unsigned)row0;
  float xp0 = io[ioff], xp1 = io[ioff + 16u];

  __syncthreads();

  for (int t = 0; t < TP; ++t) {
    // ---- issue kk15 L2 stream at step-top (consumed last) ----
    f16x8 sw0 = *(const f16x8*)(rbase + 15 * 32);
    f16x8 sw1 = *(const f16x8*)(rbase + 8192 + 15 * 32);
    f32x4 a0 = {}, a1 = {};
    __builtin_amdgcn_s_setprio(1);
    // ---- kk 0..10: zero-region broadcast af + register-resident B ----
#pragma unroll
    for (int kk = 0; kk < 11; ++kk) {
      f16x8 af = *(const f16x8*)(pc + kk * 32);
      a0 = __builtin_amdgcn_mfma_f32_16x16x32_f16(af, rs[kk][0], a0, 0, 0, 0);
      a1 = __builtin_amdgcn_mfma_f32_16x16x32_f16(af, rs[kk][1], a1, 0, 0, 0);
    }
    // ---- kk 11..14: B from LDS tile (permuted rows, swizzled slots) ----
#pragma unroll
    for (int g = 0; g < 4; ++g) {
      f16x8 bf0 = *(const f16x8*)(r4base + g * 32768);
      f16x8 bf1 = *(const f16x8*)(r4base + g * 32768 + 1024);
      f16x8 af  = *(const f16x8*)(pc + (11 + g) * 32);
      a0 = __builtin_amdgcn_mfma_f32_16x16x32_f16(af, bf0, a0, 0, 0, 0);
      a1 = __builtin_amdgcn_mfma_f32_16x16x32_f16(af, bf1, a1, 0, 0, 0);
    }
    // ---- kk 15: streamed B ----
    {
      f16x8 af = *(const f16x8*)(pc + 15 * 32);
      a0 = __builtin_amdgcn_mfma_f32_16x16x32_f16(af, sw0, a0, 0, 0, 0);
      a1 = __builtin_amdgcn_mfma_f32_16x16x32_f16(af, sw1, a1, 0, 0, 0);
    }
    __builtin_amdgcn_s_setprio(0);
    // ---- pre-barrier epilogue: the true dependency (state -> SR) only ----
    float o0 = a0[0] + xp0;
    float o1 = a1[0] + xp1;
    float n0 = __builtin_amdgcn_rcpf(1.f + __builtin_amdgcn_exp2f(-4.3280850f * o0));
    float n1 = __builtin_amdgcn_rcpf(1.f + __builtin_amdgcn_exp2f(-4.3280850f * o1));
    float g0 = __builtin_amdgcn_rcpf(1.f + __builtin_amdgcn_exp2f((2.f * n0 - 1.f) * 1.4426950f));
    float g1 = __builtin_amdgcn_rcpf(1.f + __builtin_amdgcn_exp2f((2.f * n1 - 1.f) * 1.4426950f));
    if (active) {
      f16x2 sv; sv.x = (f16)(o0 * g0); sv.y = (f16)(o1 * g1);
      *(f16x2*)wc = sv;                         // pi-layout state write
    }
    // Single barrier per step: drain LDS (state write) only; global stores
    // are disjoint-address and never drained in-loop.
    asm volatile("s_waitcnt lgkmcnt(0)\n\ts_barrier" ::: "memory");
    // ---- post-barrier: io stores + xp prefetch overlap next MFMA phase ----
    if (active) {
      io[ioff]       = n0;                      // n overwrites Xp
      io[ioff + 16u] = n1;
    }
    ioff += 512u;
    if (t < TP - 1) {                           // prefetch Xp[t+1]
      xp0 = io[ioff]; xp1 = io[ioff + 16u];
    }
    const f16* tp = pc; pc = pn; pn = tp;
    f16* tw = wc; wc = wn; wn = tw;
  }
}

// ---------------------------------------------------------------------------
extern "C" void kernel_launch(void* const* d_in, const int* in_sizes, int n_in,
                              void* d_out, int out_size, void* d_ws, size_t ws_size,
                              hipStream_t stream) {
  (void)in_sizes; (void)n_in; (void)out_size; (void)ws_size;
  const float* x     = (const float*)d_in[0];
  const float* psc_w = (const float*)d_in[1];
  const float* psc_b = (const float*)d_in[2];
  const float* kern  = (const float*)d_in[3];
  const float* rec   = (const float*)d_in[4];
  const float* bias  = (const float*)d_in[5];
  float* out = (float*)d_out;
  char* ws = (char*)d_ws;
  // ws layout: syn f16 (258304*512*2 = 264,503,296 B) | Kt f16 512KB | Rt f16 512KB
  f16* syn = (f16*)ws;
  f16* Kt  = (f16*)(ws + 264503296ull);
  f16* Rt  = (f16*)(ws + 265027584ull);

  k_convert<<<2048, 256, 0, stream>>>(kern, rec, Kt, Rt);
  k_conv   <<<2048, 256, 0, stream>>>(x, psc_w, psc_b, syn);
  k_gemm   <<<2018 * 4, 256, 0, stream>>>(syn, Kt, bias, out);
  k_rnn    <<<256, 1024, 0, stream>>>(Rt, out);
}